// Round 6
// baseline (301.228 us; speedup 1.0000x reference)
//
#include <hip/hip_runtime.h>
#include <hip/hip_bf16.h>

// GraphSAGE 2-layer, N=100K, E=1.6M, 128->128(relu)->64, log_softmax. fp32 in/out.
//
//   p = fp8(x@Wl1); q = bf16(x@Wr1 + b1)    (MFMA proj, operand-swapped, || scatter)
//   h = bf16(relu(mean_nbr(p) + q))          (bucket-fused CSR-build + gather)
//   u = fp8(h@Wl2); v = bf16(h@Wr2 + b2)     (MFMA proj)
//   out = log_softmax(mean_nbr(u) + v)       (gather u fp8, 8 lanes/edge)
//
// r5 lesson: the fp8 gather runs at a ~2.3-2.6 TB/s random-access ceiling beyond L2;
// wider loads don't help. r6 attacks pipeline serialization instead:
//  - K1 split-grid: blocks [0,NSC) bucket-scatter edges, blocks [NSC,..) proj1 (MFMA).
//  - K2 per-128-node-bucket: build bucket-local CSR wholly in LDS (no global scan, no
//    ssrc round-trip) then aggregate wave-per-node from LDS index list. src written
//    back into bbuf in CSR order for reuse by agg_lsm (row_start = b*BCAP+local).

typedef __attribute__((ext_vector_type(8))) short short8;   // 8 x bf16 = 4 VGPRs
typedef __attribute__((ext_vector_type(4))) float f32x4;
typedef __attribute__((ext_vector_type(2))) float f32x2;

#define NPB 128          // nodes per bucket (dst >> 7)
#define BCAP 3072        // edge cap per bucket (mean 2048, +22 sigma)
#define CHUNK 8192       // edges per scatter block
#define MAXNB 1024       // max buckets (N <= 131072)

__device__ __forceinline__ ushort f2bf(float f) {           // round-to-nearest-even
    unsigned u = __float_as_uint(f);
    return (ushort)((u + 0x7fff + ((u >> 16) & 1)) >> 16);
}
__device__ __forceinline__ float bflo(unsigned v) { return __uint_as_float(v << 16); }
__device__ __forceinline__ float bfhi(unsigned v) { return __uint_as_float(v & 0xffff0000u); }
__device__ __forceinline__ unsigned pk4bf(float a, float b) {
    return (unsigned)f2bf(a) | ((unsigned)f2bf(b) << 16);
}
__device__ __forceinline__ f32x2 shflx2(f32x2 v, int m) {
    f32x2 r; r[0] = __shfl_xor(v[0], m); r[1] = __shfl_xor(v[1], m); return r;
}

// ---------- weight repack into MFMA fragment order ---------------------------------
// idx = ((ct*16 + kc)*16 + m)*8 + j holds W[k=kc*8+j][c=ct*16+m]
__device__ __forceinline__ void wfrag_one(const float* W, ushort* Wf, int i, int COLS) {
    int j = i & 7, m = (i >> 3) & 15, kc = (i >> 7) & 15, ct = i >> 11;
    Wf[i] = f2bf(W[(kc * 8 + j) * COLS + ct * 16 + m]);
}
__global__ void cvt_w_kernel(const float* __restrict__ Wl1, const float* __restrict__ Wr1,
                             const float* __restrict__ Wl2, const float* __restrict__ Wr2,
                             ushort* __restrict__ Wf_l1, ushort* __restrict__ Wf_r1,
                             ushort* __restrict__ Wf_l2, ushort* __restrict__ Wf_r2) {
    int i = blockIdx.x * blockDim.x + threadIdx.x;   // 49152 total
    if (i < 16384)       wfrag_one(Wl1, Wf_l1, i, 128);
    else if (i < 32768)  wfrag_one(Wr1, Wf_r1, i - 16384, 128);
    else if (i < 40960)  wfrag_one(Wl2, Wf_l2, i - 32768, 64);
    else if (i < 49152)  wfrag_one(Wr2, Wf_r2, i - 40960, 64);
}

// ---------- dual projection body: p = fp8(X@Wl), q = bf16(X@Wr + b) ----------------
// Operand-swapped MFMA: D = Wfrag(A) * Xfrag(B) => lane holds 4 consecutive output
// cols of one node per ct => p packs to one dword (4xfp8), q to 8B (4xbf16).
template <int COLS, bool F32IN>
__device__ __forceinline__ void proj_body(int bid, int tid,
                            const void* __restrict__ xin,
                            const ushort* __restrict__ Wfl, const ushort* __restrict__ Wfr,
                            const float* __restrict__ bias,
                            unsigned char* __restrict__ p8, ushort* __restrict__ q, int N) {
    constexpr int CT = COLS / 16;
    int wave = tid >> 6, lane = tid & 63;
    int quad = lane >> 4, m = lane & 15;
    long row0 = (long)bid * 64 + wave * 16;
    long node = row0 + m;
    long arow = (node < N) ? node : (N - 1);

    f32x4 accp[CT], accq[CT];
#pragma unroll
    for (int ct = 0; ct < CT; ++ct) { accp[ct] = (f32x4)0.0f; accq[ct] = (f32x4)0.0f; }

#pragma unroll
    for (int kk = 0; kk < 128; kk += 32) {
        short8 b;                            // B-frag: B[k][n=lane&15] = x[node][k]
        if (F32IN) {
            const float* xf = (const float*)xin + arow * 128 + kk + quad * 8;
            float4 f0 = *(const float4*)xf;
            float4 f1 = *(const float4*)(xf + 4);
            b[0] = (short)f2bf(f0.x); b[1] = (short)f2bf(f0.y);
            b[2] = (short)f2bf(f0.z); b[3] = (short)f2bf(f0.w);
            b[4] = (short)f2bf(f1.x); b[5] = (short)f2bf(f1.y);
            b[6] = (short)f2bf(f1.z); b[7] = (short)f2bf(f1.w);
        } else {
            b = *(const short8*)((const ushort*)xin + arow * 128 + kk + quad * 8);
        }
        int kc = (kk >> 3) + quad;
#pragma unroll
        for (int ct = 0; ct < CT; ++ct) {
            long boff = (((long)(ct * 16 + kc) * 16) + m) * 8;
            short8 al = *(const short8*)(Wfl + boff);   // A-frag (weights)
            short8 ar = *(const short8*)(Wfr + boff);
            accp[ct] = __builtin_amdgcn_mfma_f32_16x16x32_bf16(al, b, accp[ct], 0, 0, 0);
            accq[ct] = __builtin_amdgcn_mfma_f32_16x16x32_bf16(ar, b, accq[ct], 0, 0, 0);
        }
    }

    if (node < N) {
#pragma unroll
        for (int ct = 0; ct < CT; ++ct) {
            int c0 = ct * 16 + quad * 4;
            float4 bv = *(const float4*)(bias + c0);
            float q0 = accq[ct][0] + bv.x, q1 = accq[ct][1] + bv.y;
            float q2 = accq[ct][2] + bv.z, q3 = accq[ct][3] + bv.w;
            unsigned w = (unsigned)__builtin_amdgcn_cvt_pk_fp8_f32(accp[ct][0], accp[ct][1], 0, false);
            w = (unsigned)__builtin_amdgcn_cvt_pk_fp8_f32(accp[ct][2], accp[ct][3], (int)w, true);
            *(unsigned*)(p8 + node * COLS + c0) = w;
            uint2 qw; qw.x = pk4bf(q0, q1); qw.y = pk4bf(q2, q3);
            *(uint2*)(q + node * COLS + c0) = qw;
        }
    }
}

// ---------- K1: fused [bucket_scatter | proj1] split grid --------------------------
// entry = (src << 7) | (dst & 127), bucket = dst >> 7.
__global__ void __launch_bounds__(256)
fused_scatter_proj1(const int* __restrict__ src, const int* __restrict__ dst,
                    int* __restrict__ bcount, int* __restrict__ bbuf, int E, int NB, int NSC,
                    const float* __restrict__ x,
                    const ushort* __restrict__ Wfl, const ushort* __restrict__ Wfr,
                    const float* __restrict__ bias,
                    unsigned char* __restrict__ p8, ushort* __restrict__ q, int N) {
    __shared__ int lhist[MAXNB], lbase[MAXNB], lcur[MAXNB];
    int tid = threadIdx.x;
    if ((int)blockIdx.x >= NSC) {
        proj_body<128, true>((int)blockIdx.x - NSC, tid, x, Wfl, Wfr, bias, p8, q, N);
        return;
    }
    // ---- scatter path ----
    for (int i = tid; i < NB; i += 256) lhist[i] = 0;
    __syncthreads();
    int e0 = blockIdx.x * CHUNK;
    int cnt = min(CHUNK, E - e0);
    int nv = cnt >> 2;
    for (int t = tid; t < nv; t += 256) {
        int4 d4 = ((const int4*)(dst + e0))[t];
        atomicAdd(&lhist[d4.x >> 7], 1); atomicAdd(&lhist[d4.y >> 7], 1);
        atomicAdd(&lhist[d4.z >> 7], 1); atomicAdd(&lhist[d4.w >> 7], 1);
    }
    for (int i = (nv << 2) + tid; i < cnt; i += 256)
        atomicAdd(&lhist[dst[e0 + i] >> 7], 1);
    __syncthreads();
    for (int i = tid; i < NB; i += 256) {
        int h = lhist[i];
        lbase[i] = (h > 0) ? atomicAdd(&bcount[i], h) : 0;
        lcur[i] = 0;
    }
    __syncthreads();
    for (int t = tid; t < nv; t += 256) {
        int4 d4 = ((const int4*)(dst + e0))[t];
        int4 s4 = ((const int4*)(src + e0))[t];
#pragma unroll
        for (int j = 0; j < 4; ++j) {
            int d = (j == 0) ? d4.x : (j == 1) ? d4.y : (j == 2) ? d4.z : d4.w;
            int s = (j == 0) ? s4.x : (j == 1) ? s4.y : (j == 2) ? s4.z : s4.w;
            int b = d >> 7;
            int pos = lbase[b] + atomicAdd(&lcur[b], 1);
            if (pos < BCAP) bbuf[(long)b * BCAP + pos] = (s << 7) | (d & 127);
        }
    }
    for (int i = (nv << 2) + tid; i < cnt; i += 256) {
        int d = dst[e0 + i], s = src[e0 + i];
        int b = d >> 7;
        int pos = lbase[b] + atomicAdd(&lcur[b], 1);
        if (pos < BCAP) bbuf[(long)b * BCAP + pos] = (s << 7) | (d & 127);
    }
}

// ---------- K2: per-bucket CSR build (in LDS) + layer-1 aggregate ------------------
// h = bf16(relu(mean_nbr(p) + q)). Writes src back to bbuf in CSR order for agg_lsm;
// row_start[node] = b*BCAP + local offset.
__global__ void __launch_bounds__(256)
csr_agg_kernel(int* __restrict__ bbuf, const int* __restrict__ bcount,
               const unsigned char* __restrict__ p8, const ushort* __restrict__ q,
               int* __restrict__ row_start, int* __restrict__ degw,
               float* __restrict__ inv_deg, ushort* __restrict__ hb, int N) {
    __shared__ int lent[BCAP];       // 12 KB staged entries
    __shared__ int lssrc[BCAP];      // 12 KB CSR-ordered srcs
    __shared__ int ldeg[NPB], lrs[NPB], lc[NPB];
    int b = blockIdx.x, tid = threadIdx.x;
    int cnt = min(bcount[b], BCAP);
    long base = (long)b * BCAP;
    if (tid < NPB) ldeg[tid] = 0;
    __syncthreads();
    for (int i = tid; i < cnt; i += 256) {
        int e = bbuf[base + i];
        lent[i] = e;
        atomicAdd(&ldeg[e & 127], 1);
    }
    __syncthreads();
    if (tid < NPB) lrs[tid] = ldeg[tid];
    __syncthreads();
    for (int off = 1; off < NPB; off <<= 1) {   // inclusive Hillis-Steele over 128
        int a = (tid < NPB && tid >= off) ? lrs[tid - off] : 0;
        __syncthreads();
        if (tid < NPB) lrs[tid] += a;
        __syncthreads();
    }
    if (tid < NPB) {
        int d = ldeg[tid];
        int rs = lrs[tid] - d;                  // exclusive
        lrs[tid] = rs;
        lc[tid] = rs;
        int node = b * NPB + tid;
        if (node < N) {
            row_start[node] = (int)(base + rs);
            degw[node] = d;
            inv_deg[node] = 1.0f / (float)(d > 1 ? d : 1);
        }
    }
    __syncthreads();
    for (int i = tid; i < cnt; i += 256) {
        int e = lent[i];
        int pos = atomicAdd(&lc[e & 127], 1);
        int s = e >> 7;
        lssrc[pos] = s;
        bbuf[base + pos] = s;                   // CSR-ordered srcs for agg_lsm
    }
    __syncthreads();

    // ---- aggregate: wave-per-node, 16 lanes/edge, 8B/lane (4 rows per instr) ----
    int wv = tid >> 6, ln = tid & 63;
    int g = ln >> 4, lm = ln & 15;
    const unsigned char* pb = p8 + lm * 8;
    for (int nl = wv; nl < NPB; nl += 4) {
        int node = b * NPB + nl;
        if (node >= N) break;
        int rs = lrs[nl], d = ldeg[nl];
        f32x2 a0 = (f32x2)0.f, a1 = (f32x2)0.f, a2 = (f32x2)0.f, a3 = (f32x2)0.f;
        int j = 0;
        for (; j + 16 <= d; j += 16) {
            int s0 = lssrc[rs + j + g],      s1 = lssrc[rs + j + 4 + g];
            int s2 = lssrc[rs + j + 8 + g],  s3 = lssrc[rs + j + 12 + g];
            uint2 v0 = *(const uint2*)(pb + (long)s0 * 128);
            uint2 v1 = *(const uint2*)(pb + (long)s1 * 128);
            uint2 v2 = *(const uint2*)(pb + (long)s2 * 128);
            uint2 v3 = *(const uint2*)(pb + (long)s3 * 128);
#pragma unroll
            for (int t = 0; t < 4; ++t) {
                uint2 vv = (t == 0) ? v0 : (t == 1) ? v1 : (t == 2) ? v2 : v3;
                a0 += __builtin_amdgcn_cvt_pk_f32_fp8((int)vv.x, false);
                a1 += __builtin_amdgcn_cvt_pk_f32_fp8((int)vv.x, true);
                a2 += __builtin_amdgcn_cvt_pk_f32_fp8((int)vv.y, false);
                a3 += __builtin_amdgcn_cvt_pk_f32_fp8((int)vv.y, true);
            }
        }
        for (; j < d; j += 4) {                 // predicated tail, 4 edges/iter
            int idx = j + g;
            int s = lssrc[rs + (idx < d ? idx : j)];
            uint2 vv = *(const uint2*)(pb + (long)s * 128);
            if (idx < d) {
                a0 += __builtin_amdgcn_cvt_pk_f32_fp8((int)vv.x, false);
                a1 += __builtin_amdgcn_cvt_pk_f32_fp8((int)vv.x, true);
                a2 += __builtin_amdgcn_cvt_pk_f32_fp8((int)vv.y, false);
                a3 += __builtin_amdgcn_cvt_pk_f32_fp8((int)vv.y, true);
            }
        }
        a0 += shflx2(a0, 16); a1 += shflx2(a1, 16);
        a2 += shflx2(a2, 16); a3 += shflx2(a3, 16);
        a0 += shflx2(a0, 32); a1 += shflx2(a1, 32);
        a2 += shflx2(a2, 32); a3 += shflx2(a3, 32);
        if (g == 0) {
            float iv = inv_deg[node];
            uint4 qv = *(const uint4*)(q + (long)node * 128 + lm * 8);
            float h0 = fmaxf(a0[0] * iv + bflo(qv.x), 0.f);
            float h1 = fmaxf(a0[1] * iv + bfhi(qv.x), 0.f);
            float h2 = fmaxf(a1[0] * iv + bflo(qv.y), 0.f);
            float h3 = fmaxf(a1[1] * iv + bfhi(qv.y), 0.f);
            float h4 = fmaxf(a2[0] * iv + bflo(qv.z), 0.f);
            float h5 = fmaxf(a2[1] * iv + bfhi(qv.z), 0.f);
            float h6 = fmaxf(a3[0] * iv + bflo(qv.w), 0.f);
            float h7 = fmaxf(a3[1] * iv + bfhi(qv.w), 0.f);
            uint4 hw;
            hw.x = pk4bf(h0, h1); hw.y = pk4bf(h2, h3);
            hw.z = pk4bf(h4, h5); hw.w = pk4bf(h6, h7);
            *(uint4*)(hb + (long)node * 128 + lm * 8) = hw;
        }
    }
}

// ---------- proj2 (standalone) -----------------------------------------------------
__global__ void __launch_bounds__(256)
proj2_kernel(const ushort* __restrict__ hb,
             const ushort* __restrict__ Wfl, const ushort* __restrict__ Wfr,
             const float* __restrict__ bias,
             unsigned char* __restrict__ u8, ushort* __restrict__ v, int N) {
    proj_body<64, false>((int)blockIdx.x, (int)threadIdx.x, hb, Wfl, Wfr, bias, u8, v, N);
}

// ---------- layer-2 aggregate + log_softmax ----------------------------------------
// One wave per node; 8 lanes per edge, 8B/lane: one instr = 8 rows (512B).
__global__ void agg_lsm_kernel(const unsigned char* __restrict__ u8,   // N x 64 fp8
                               const ushort* __restrict__ v,           // N x 64 bf16
                               const int* __restrict__ ssrc,           // = bbuf
                               const int* __restrict__ row_start,
                               const int* __restrict__ deg,
                               const float* __restrict__ inv_deg,
                               float* __restrict__ out, int N) {
    int wave = threadIdx.x >> 6, lane = threadIdx.x & 63;
    int n = blockIdx.x * 4 + wave;
    if (n >= N) return;
    int g = lane >> 3, lm = lane & 7;              // edge slot / cols lm*8..lm*8+7
    int start = row_start[n], d = deg[n];
    const int* sp = ssrc + start;
    const unsigned char* ub = u8 + lm * 8;
    f32x2 a0 = (f32x2)0.f, a1 = (f32x2)0.f, a2 = (f32x2)0.f, a3 = (f32x2)0.f;
    int j = 0;
    for (; j + 16 <= d; j += 16) {                 // 2 row loads = 16 edges in flight
        int s0 = sp[j + g], s1 = sp[j + 8 + g];
        uint2 v0 = *(const uint2*)(ub + (long)s0 * 64);
        uint2 v1 = *(const uint2*)(ub + (long)s1 * 64);
#pragma unroll
        for (int t = 0; t < 2; ++t) {
            uint2 vv = (t == 0) ? v0 : v1;
            a0 += __builtin_amdgcn_cvt_pk_f32_fp8((int)vv.x, false);
            a1 += __builtin_amdgcn_cvt_pk_f32_fp8((int)vv.x, true);
            a2 += __builtin_amdgcn_cvt_pk_f32_fp8((int)vv.y, false);
            a3 += __builtin_amdgcn_cvt_pk_f32_fp8((int)vv.y, true);
        }
    }
    for (; j < d; j += 8) {                        // predicated tail, 8 edges/iter
        int idx = j + g;
        int s = sp[idx < d ? idx : j];
        uint2 vv = *(const uint2*)(ub + (long)s * 64);
        if (idx < d) {
            a0 += __builtin_amdgcn_cvt_pk_f32_fp8((int)vv.x, false);
            a1 += __builtin_amdgcn_cvt_pk_f32_fp8((int)vv.x, true);
            a2 += __builtin_amdgcn_cvt_pk_f32_fp8((int)vv.y, false);
            a3 += __builtin_amdgcn_cvt_pk_f32_fp8((int)vv.y, true);
        }
    }
    a0 += shflx2(a0, 8);  a1 += shflx2(a1, 8);  a2 += shflx2(a2, 8);  a3 += shflx2(a3, 8);
    a0 += shflx2(a0, 16); a1 += shflx2(a1, 16); a2 += shflx2(a2, 16); a3 += shflx2(a3, 16);
    a0 += shflx2(a0, 32); a1 += shflx2(a1, 32); a2 += shflx2(a2, 32); a3 += shflx2(a3, 32);

    float iv = inv_deg[n];
    uint4 vv = *(const uint4*)(v + (long)n * 64 + lm * 8);
    float z0 = a0[0] * iv + bflo(vv.x), z1 = a0[1] * iv + bfhi(vv.x);
    float z2 = a1[0] * iv + bflo(vv.y), z3 = a1[1] * iv + bfhi(vv.y);
    float z4 = a2[0] * iv + bflo(vv.z), z5 = a2[1] * iv + bfhi(vv.z);
    float z6 = a3[0] * iv + bflo(vv.w), z7 = a3[1] * iv + bfhi(vv.w);
    float mx = fmaxf(fmaxf(fmaxf(z0, z1), fmaxf(z2, z3)),
                     fmaxf(fmaxf(z4, z5), fmaxf(z6, z7)));
#pragma unroll
    for (int o = 4; o > 0; o >>= 1) mx = fmaxf(mx, __shfl_xor(mx, o));   // over lm bits
    float e = (__expf(z0 - mx) + __expf(z1 - mx)) + (__expf(z2 - mx) + __expf(z3 - mx)) +
              (__expf(z4 - mx) + __expf(z5 - mx)) + (__expf(z6 - mx) + __expf(z7 - mx));
#pragma unroll
    for (int o = 4; o > 0; o >>= 1) e += __shfl_xor(e, o);
    float ls = mx + __logf(e);
    if (g == 0) {                                  // 8 lanes store 8 floats each
        float4 o0, o1;
        o0.x = z0 - ls; o0.y = z1 - ls; o0.z = z2 - ls; o0.w = z3 - ls;
        o1.x = z4 - ls; o1.y = z5 - ls; o1.z = z6 - ls; o1.w = z7 - ls;
        *(float4*)(out + (long)n * 64 + lm * 8) = o0;
        *(float4*)(out + (long)n * 64 + lm * 8 + 4) = o1;
    }
}

// -----------------------------------------------------------------------------------
extern "C" void kernel_launch(void* const* d_in, const int* in_sizes, int n_in,
                              void* d_out, int out_size, void* d_ws, size_t ws_size,
                              hipStream_t stream) {
    const float* x   = (const float*)d_in[0];
    const int*   ei  = (const int*)d_in[1];
    const float* Wl1 = (const float*)d_in[2];
    const float* Wr1 = (const float*)d_in[3];
    const float* b1  = (const float*)d_in[4];
    const float* Wl2 = (const float*)d_in[5];
    const float* Wr2 = (const float*)d_in[6];
    const float* b2  = (const float*)d_in[7];

    const int N = in_sizes[0] / 128;
    const int E = in_sizes[1] / 2;
    const int* src = ei;
    const int* dst = ei + E;
    const int NB = (N + NPB - 1) / NPB;             // 782 buckets for N=100000
    const int NSC = (E + CHUNK - 1) / CHUNK;        // 196 scatter blocks

    size_t off = 0;
    auto take = [&](size_t nbytes) -> void* {
        void* ptr = (void*)((char*)d_ws + off);
        off += (nbytes + 255) & ~(size_t)255;
        return ptr;
    };
    int*      bcount    = (int*)take((size_t)NB * 4);
    int*      bbuf      = (int*)take((size_t)NB * BCAP * 4);        // ~9.6 MB
    int*      row_start = (int*)take((size_t)N * 4);
    int*      degw      = (int*)take((size_t)N * 4);
    float*    inv_deg   = (float*)take((size_t)N * 4);
    unsigned char* p8   = (unsigned char*)take((size_t)N * 128);    // reused as u8
    ushort*   q         = (ushort*)take((size_t)N * 128 * 2);       // reused as v
    ushort*   hb        = (ushort*)take((size_t)N * 128 * 2);
    ushort*   Wf_l1     = (ushort*)take(128 * 128 * 2);
    ushort*   Wf_r1     = (ushort*)take(128 * 128 * 2);
    ushort*   Wf_l2     = (ushort*)take(64 * 128 * 2);
    ushort*   Wf_r2     = (ushort*)take(64 * 128 * 2);
    unsigned char* u8 = p8;   // p dead after csr_agg
    ushort*        v  = q;    // q dead after csr_agg
    (void)ws_size; (void)n_in; (void)out_size;

    hipMemsetAsync(bcount, 0, (size_t)NB * 4, stream);

    cvt_w_kernel<<<192, 256, 0, stream>>>(Wl1, Wr1, Wl2, Wr2, Wf_l1, Wf_r1, Wf_l2, Wf_r2);

    // K1: scatter (blocks 0..NSC) || proj1 (rest)
    int P1 = (N + 63) / 64;
    fused_scatter_proj1<<<NSC + P1, 256, 0, stream>>>(src, dst, bcount, bbuf, E, NB, NSC,
                                                      x, Wf_l1, Wf_r1, b1, p8, q, N);

    // K2: per-bucket CSR build (LDS) + layer-1 aggregate
    csr_agg_kernel<<<NB, 256, 0, stream>>>(bbuf, bcount, p8, q, row_start, degw, inv_deg, hb, N);

    // layer 2
    proj2_kernel<<<(N + 63) / 64, 256, 0, stream>>>(hb, Wf_l2, Wf_r2, b2, u8, v, N);
    agg_lsm_kernel<<<(N + 3) / 4, 256, 0, stream>>>(u8, v, (const int*)bbuf, row_start, degw,
                                                    inv_deg, (float*)d_out, N);
}